// Round 8
// baseline (5307.896 us; speedup 1.0000x reference)
//
#include <hip/hip_runtime.h>
#include <cstdint>

// ---------------------------------------------------------------------------
// Threefry-2x32 (JAX partitionable-mode compatible), host + device.
// ---------------------------------------------------------------------------
__host__ __device__ inline uint32_t tf_rotl32(uint32_t x, uint32_t r) {
  return (x << r) | (x >> (32u - r));
}

__host__ __device__ inline void threefry2x32(uint32_t k0, uint32_t k1,
                                             uint32_t x0, uint32_t x1,
                                             uint32_t* o0, uint32_t* o1) {
  uint32_t ks0 = k0, ks1 = k1, ks2 = k0 ^ k1 ^ 0x1BD11BDAu;
  x0 += ks0; x1 += ks1;
#define TF_R(r) { x0 += x1; x1 = tf_rotl32(x1, r); x1 ^= x0; }
  TF_R(13) TF_R(15) TF_R(26) TF_R(6)
  x0 += ks1; x1 += ks2 + 1u;
  TF_R(17) TF_R(29) TF_R(16) TF_R(24)
  x0 += ks2; x1 += ks0 + 2u;
  TF_R(13) TF_R(15) TF_R(26) TF_R(6)
  x0 += ks0; x1 += ks1 + 3u;
  TF_R(17) TF_R(29) TF_R(16) TF_R(24)
  x0 += ks1; x1 += ks2 + 4u;
  TF_R(13) TF_R(15) TF_R(26) TF_R(6)
  x0 += ks2; x1 += ks0 + 5u;
#undef TF_R
  *o0 = x0; *o1 = x1;
}

// ---------------------------------------------------------------------------
// Problem dims
// ---------------------------------------------------------------------------
#define BSZ   8192
#define KIN   784
#define HID   800
#define NOUT  10
#define NSTEP 25

// R8: golden = Eigen gebp (AVX no-FMA jaxlib): k-panels [0,264) [264,528)
// [528,784), per k-step acc = rn(acc + rn(a*b)).
// R9: a in {0,1,2} makes every product exact, so fmaf == mul+add bit-exactly.
// R13/R15: conflicts->0, pk_fma (24 cyc/kk) — dur stuck ~170us. Budget:
//   per kk/wave LDS = b32+b128 ~ 18 cyc per 1024 MAC -> 147us LDS-pipe wall
//   (4 SIMDs share 1 LDS unit) vs 49us VALU. KERNEL IS LDS-ISSUE BOUND.
// R16 (this round): halve LDS instr/MAC — 8x4 thread tile (BM=256, BN=32,
//   256 thr): per kk A=ds_read_b64 (8 packed rows) + B=ds_read_b128 per
//   2048 MAC -> LDS wall ~77us, VALU ~49us. R4's latency failure countered
//   by pk_fma + explicit kk software pipeline (prefetch kk+1 frags) +
//   R13 dbuf/split-staging. Predict gemm 169 -> 105-135us.
// ---------------------------------------------------------------------------
#define PANEL1 264
#define PANEL2 528

// ---------------------------------------------------------------------------
// Kernel 1: Poisson encoding (JAX-faithful: truncated 2^-23 grid).
// enc = temp + 1 in {0,1,2}; sp = 0.5*enc (exact power-of-2 relation).
// ---------------------------------------------------------------------------
__global__ __launch_bounds__(256) void enc_kernel(const float* __restrict__ inp,
                                                  uint8_t* __restrict__ enc,
                                                  uint32_t k0, uint32_t k1) {
  int j = blockIdx.x * blockDim.x + threadIdx.x;
  if (j >= BSZ * KIN) return;
  uint32_t o0, o1;
  threefry2x32(k0, k1, 0u, (uint32_t)j, &o0, &o1);
  uint32_t bits = o0 ^ o1;
  float r = __uint_as_float((bits >> 9) | 0x3f800000u) - 1.0f;
  float x = inp[j];
  bool cond = (2.0f * r <= fabsf(x));
  int s = (x > 0.0f) ? 1 : ((x < 0.0f) ? -1 : 0);
  enc[j] = (uint8_t)(1 + (cond ? s : 0));
}

// ---------------------------------------------------------------------------
// Kernel 2: g[b,j] = 0.5 * ((P0 + P1) + P2), Eigen panels at k=264,528.
// BM=256, BN=32, BK=16. 256 threads (4 waves), 8x4 acc per thread.
// As: packed u8 [2][BK][BM/4 words] (byte i of word r = A[row 4r+i][k]).
// Bs: f32 [2][BK][BN]. Double-buffered; all threads stage A, t<128 stage B.
// Per kk: ds_read_b64 (A, 8 rows) + ds_read_b128 (B) + 8 cvt + 16 pk_fma.
// ---------------------------------------------------------------------------
#define BM 256
#define BN 32
#define BK 16
#define NTILE (KIN / BK)   // 49

typedef float f32x2 __attribute__((ext_vector_type(2)));

__device__ __forceinline__ float cvt_ub(uint32_t x, int i) {
  return (float)((x >> (8 * i)) & 0xffu);   // folds to v_cvt_f32_ubyte_i
}

// acc.lo = fma(a.lo, b.lo, acc.lo); acc.hi = fma(a.lo, b.hi, acc.hi)
// Per-half rounding == v_fma_f32 (bit-exact); src0 half broadcast via op_sel.
__device__ __forceinline__ void pk_fma_lo(f32x2& acc, f32x2 a, f32x2 b) {
  asm("v_pk_fma_f32 %0, %1, %2, %0 op_sel:[0,0,0] op_sel_hi:[0,1,1]"
      : "+v"(acc)
      : "v"(a), "v"(b));
}
// same but broadcasting src0.hi
__device__ __forceinline__ void pk_fma_hi(f32x2& acc, f32x2 a, f32x2 b) {
  asm("v_pk_fma_f32 %0, %1, %2, %0 op_sel:[1,0,0] op_sel_hi:[1,1,1]"
      : "+v"(acc)
      : "v"(a), "v"(b));
}

__global__ __launch_bounds__(256) void gemm_kernel(const uint8_t* __restrict__ enc,
                                                   const float* __restrict__ w1,
                                                   float* __restrict__ g) {
  __shared__ uint32_t As[2][BK][BM / 4];  // 2 x 4 KB
  __shared__ float    Bs[2][BK][BN];      // 2 x 2 KB
  const int m0 = blockIdx.x * BM;
  const int n0 = blockIdx.y * BN;
  const int t  = threadIdx.x;

  // compute mapping: 32 row-groups (8 rows each) x 8 col-groups (4 cols)
  const int tm = t / 8;        // 0..31 -> rows tm*8 .. +7
  const int tn = t % 8;        // 0..7  -> cols tn*4 .. +3

  // staging: ALL threads stage A (4 rows x 4 k bytes each);
  //          threads 0..127 also stage B (1 row x 4 k f32 each).
  const int ar0  = (t & 63) * 4;       // A: row base 0..252
  const int ak0  = (t >> 6) * 4;       // A: k base 0,4,8,12
  const bool isB = (t < 128);
  const int brow = t & 31;             // B: row 0..31
  const int bk0  = ((t >> 5) & 3) * 4; // B: k base 0,4,8,12

  const uint8_t* aptr = enc + (size_t)(m0 + ar0) * KIN + ak0;
  const float*   bptr = w1 + (size_t)(n0 + brow) * KIN + bk0;

  uint32_t rA0, rA1, rA2, rA3;
  float4 rB;

  f32x2 acc[8][2];   // current panel chain: [mi][nj] covers cols 2nj,2nj+1
  f32x2 tot[8][2];   // committed C (valid after first commit)
#pragma unroll
  for (int mi = 0; mi < 8; mi++)
#pragma unroll
    for (int nj = 0; nj < 2; nj++) acc[mi][nj] = (f32x2)(0.0f);

#define LOAD_TILE(K0G)                                               \
  {                                                                  \
    const uint8_t* ap = aptr + (K0G);                                \
    rA0 = *(const uint32_t*)(ap + (size_t)0 * KIN);                  \
    rA1 = *(const uint32_t*)(ap + (size_t)1 * KIN);                  \
    rA2 = *(const uint32_t*)(ap + (size_t)2 * KIN);                  \
    rA3 = *(const uint32_t*)(ap + (size_t)3 * KIN);                  \
    if (isB) rB = *(const float4*)(bptr + (K0G));                    \
  }

#define STORE_TILE(P)                                                \
  {                                                                  \
    uint32_t a01  = __builtin_amdgcn_perm(rA1, rA0, 0x05010400u);    \
    uint32_t a01h = __builtin_amdgcn_perm(rA1, rA0, 0x07030602u);    \
    uint32_t a23  = __builtin_amdgcn_perm(rA3, rA2, 0x05010400u);    \
    uint32_t a23h = __builtin_amdgcn_perm(rA3, rA2, 0x07030602u);    \
    As[P][ak0 + 0][ar0 >> 2] = __builtin_amdgcn_perm(a23,  a01,  0x05040100u); \
    As[P][ak0 + 1][ar0 >> 2] = __builtin_amdgcn_perm(a23,  a01,  0x07060302u); \
    As[P][ak0 + 2][ar0 >> 2] = __builtin_amdgcn_perm(a23h, a01h, 0x05040100u); \
    As[P][ak0 + 3][ar0 >> 2] = __builtin_amdgcn_perm(a23h, a01h, 0x07060302u); \
    if (isB) {                                                       \
      Bs[P][bk0 + 0][brow] = rB.x;                                   \
      Bs[P][bk0 + 1][brow] = rB.y;                                   \
      Bs[P][bk0 + 2][brow] = rB.z;                                   \
      Bs[P][bk0 + 3][brow] = rB.w;                                   \
    }                                                                \
  }

  // ---- prologue: stage tile 0 into buffer 0 ----
  LOAD_TILE(0)
  STORE_TILE(0)
  __syncthreads();

  int p = 0;
  for (int tile = 0; tile < NTILE; tile++) {
    const int kbase = tile * BK;
    const bool more = (tile + 1 < NTILE);
    // issue next tile's global loads; latency hides under compute
    if (more) { LOAD_TILE(kbase + BK) }
    // compute current tile from LDS buffer p, 1-deep kk software pipeline
    {
      const uint32_t* arow = &As[p][0][tm * 2];
      const float*    brow_ = &Bs[p][0][tn * 4];
      uint2  aw_c = *(const uint2*)arow;          // kk = 0
      float4 bv_c = *(const float4*)brow_;
#pragma unroll
      for (int kk = 0; kk < BK; kk++) {
        const int kglob = kbase + kk;
        uint2  aw_n;
        float4 bv_n;
        if (kk + 1 < BK) {   // compile-time in unrolled body
          aw_n = *(const uint2*)(arow + (size_t)(kk + 1) * (BM / 4));
          bv_n = *(const float4*)(brow_ + (size_t)(kk + 1) * BN);
        }
        if (kglob == PANEL1) {
#pragma unroll
          for (int mi = 0; mi < 8; mi++)
#pragma unroll
            for (int nj = 0; nj < 2; nj++) {
              tot[mi][nj] = acc[mi][nj];
              acc[mi][nj] = (f32x2)(0.0f);
            }
        } else if (kglob == PANEL2) {
#pragma unroll
          for (int mi = 0; mi < 8; mi++)
#pragma unroll
            for (int nj = 0; nj < 2; nj++) {
              tot[mi][nj].x = __fadd_rn(tot[mi][nj].x, acc[mi][nj].x);
              tot[mi][nj].y = __fadd_rn(tot[mi][nj].y, acc[mi][nj].y);
              acc[mi][nj] = (f32x2)(0.0f);
            }
        }
        // A fragment: 8 u8 rows (2 packed words) -> four f32 pairs
        f32x2 am[4];
        am[0].x = cvt_ub(aw_c.x, 0); am[0].y = cvt_ub(aw_c.x, 1);
        am[1].x = cvt_ub(aw_c.x, 2); am[1].y = cvt_ub(aw_c.x, 3);
        am[2].x = cvt_ub(aw_c.y, 0); am[2].y = cvt_ub(aw_c.y, 1);
        am[3].x = cvt_ub(aw_c.y, 2); am[3].y = cvt_ub(aw_c.y, 3);
        // B fragment: two f32 pairs
        f32x2 b2[2];
        b2[0].x = bv_c.x; b2[0].y = bv_c.y;
        b2[1].x = bv_c.z; b2[1].y = bv_c.w;
        // rows: mi = 2*mp + h (h = broadcast half of am[mp])
#pragma unroll
        for (int mp = 0; mp < 4; mp++) {
          pk_fma_lo(acc[2 * mp + 0][0], am[mp], b2[0]);
          pk_fma_lo(acc[2 * mp + 0][1], am[mp], b2[1]);
          pk_fma_hi(acc[2 * mp + 1][0], am[mp], b2[0]);
          pk_fma_hi(acc[2 * mp + 1][1], am[mp], b2[1]);
        }
        if (kk + 1 < BK) { aw_c = aw_n; bv_c = bv_n; }
      }
    }
    // stage next tile into the other buffer (no reader until after sync)
    if (more) { STORE_TILE(p ^ 1) }
    __syncthreads();
    p ^= 1;
  }
#undef LOAD_TILE
#undef STORE_TILE

#pragma unroll
  for (int mi = 0; mi < 8; mi++) {
    float* dst = g + (size_t)(m0 + tm * 8 + mi) * HID + n0 + tn * 4;
    float4 o;
    o.x = __fmul_rn(0.5f, __fadd_rn(tot[mi][0].x, acc[mi][0].x));  // (P0+P1)+P2, exact 0.5
    o.y = __fmul_rn(0.5f, __fadd_rn(tot[mi][0].y, acc[mi][0].y));
    o.z = __fmul_rn(0.5f, __fadd_rn(tot[mi][1].x, acc[mi][1].x));
    o.w = __fmul_rn(0.5f, __fadd_rn(tot[mi][1].y, acc[mi][1].y));
    *(float4*)dst = o;
  }
}

// ---------------------------------------------------------------------------
// Kernel 3: f32 membrane update + spike + mem2 accumulation.
// m = rn(rn(0.95f*mem) + rn(0.05f*g)) — mul/mul/add; products NOT exact here,
// so FMA contraction would change bits — keep split __fmul_rn/__fadd_rn.
// ---------------------------------------------------------------------------
__global__ __launch_bounds__(256) void update_kernel(const float* __restrict__ g,
                                                     float* __restrict__ mem1,
                                                     const float* __restrict__ w2,
                                                     float* __restrict__ mem2) {
  __shared__ float w2s[NOUT * HID];   // 32 KB
  for (int i = threadIdx.x; i < NOUT * HID; i += 256) w2s[i] = w2[i];
  __syncthreads();

  const int wave = threadIdx.x / 64;
  const int lane = threadIdx.x % 64;
  const int b = blockIdx.x * 4 + wave;

  const float* grow = g + (size_t)b * HID;
  float* mrow = mem1 + (size_t)b * HID;

  float acc[NOUT];
#pragma unroll
  for (int i = 0; i < NOUT; i++) acc[i] = 0.0f;

  for (int j = lane; j < HID; j += 64) {
    float m = __fadd_rn(__fmul_rn(0.95f, mrow[j]), __fmul_rn(0.05f, grow[j]));
    bool spike = __fadd_rn(m, -1.0f) > 0.0f;
    mrow[j] = spike ? __fadd_rn(m, -1.0f) : m;
    if (spike) {
#pragma unroll
      for (int i = 0; i < NOUT; i++) acc[i] += w2s[i * HID + j];
    }
  }
  // mem2 never feeds back into spike decisions: reduction-order noise ~1e-7
  // << 3.6e-3 threshold, no need to replicate ref's order here.
#pragma unroll
  for (int i = 0; i < NOUT; i++) {
    float v = acc[i];
    for (int off = 32; off > 0; off >>= 1) v += __shfl_down(v, off);
    if (lane == 0) mem2[(size_t)b * NOUT + i] += v;
  }
}

// ---------------------------------------------------------------------------
// Kernel 4: out = mem2 / num_steps
// ---------------------------------------------------------------------------
__global__ __launch_bounds__(256) void finalize_kernel(const float* __restrict__ mem2,
                                                       const int* __restrict__ ns,
                                                       float* __restrict__ out) {
  int i = blockIdx.x * blockDim.x + threadIdx.x;
  if (i < BSZ * NOUT) out[i] = mem2[i] / (float)(*ns);
}

// ---------------------------------------------------------------------------
extern "C" void kernel_launch(void* const* d_in, const int* in_sizes, int n_in,
                              void* d_out, int out_size, void* d_ws, size_t ws_size,
                              hipStream_t stream) {
  const float* inp = (const float*)d_in[0];
  const float* w1  = (const float*)d_in[1];
  const float* w2  = (const float*)d_in[2];
  const int*   dns = (const int*)d_in[3];
  float* out = (float*)d_out;

  char* ws = (char*)d_ws;
  size_t off = 0;
  uint8_t* enc = (uint8_t*)(ws + off);  off += (size_t)BSZ * KIN;          // 6.4 MB
  off = (off + 255) & ~(size_t)255;
  float* g    = (float*)(ws + off);     off += (size_t)BSZ * HID * 4;      // 26.2 MB
  float* mem1 = (float*)(ws + off);     off += (size_t)BSZ * HID * 4;      // 26.2 MB
  float* mem2 = (float*)(ws + off);     off += (size_t)BSZ * NOUT * 4;     // 0.33 MB

  (void)hipMemsetAsync(mem1, 0, (size_t)BSZ * HID * 4, stream);
  (void)hipMemsetAsync(mem2, 0, (size_t)BSZ * NOUT * 4, stream);

  // Step keys: partitionable split — key_t = threefry((0,42), (0,t)).
  uint32_t keys[NSTEP][2];
  for (int t = 0; t < NSTEP; t++)
    threefry2x32(0u, 42u, 0u, (uint32_t)t, &keys[t][0], &keys[t][1]);

  const int n_elem = BSZ * KIN;
  for (int t = 0; t < NSTEP; t++) {
    enc_kernel<<<(n_elem + 255) / 256, 256, 0, stream>>>(inp, enc, keys[t][0], keys[t][1]);
    gemm_kernel<<<dim3(BSZ / BM, HID / BN), 256, 0, stream>>>(enc, w1, g);
    update_kernel<<<BSZ / 4, 256, 0, stream>>>(g, mem1, w2, mem2);
  }
  finalize_kernel<<<(BSZ * NOUT + 255) / 256, 256, 0, stream>>>(mem2, dns, out);
}

// Round 9
// 4680.619 us; speedup vs baseline: 1.1340x; 1.1340x over previous
//
#include <hip/hip_runtime.h>
#include <cstdint>

// ---------------------------------------------------------------------------
// Threefry-2x32 (JAX partitionable-mode compatible), host + device.
// ---------------------------------------------------------------------------
__host__ __device__ inline uint32_t tf_rotl32(uint32_t x, uint32_t r) {
  return (x << r) | (x >> (32u - r));
}

__host__ __device__ inline void threefry2x32(uint32_t k0, uint32_t k1,
                                             uint32_t x0, uint32_t x1,
                                             uint32_t* o0, uint32_t* o1) {
  uint32_t ks0 = k0, ks1 = k1, ks2 = k0 ^ k1 ^ 0x1BD11BDAu;
  x0 += ks0; x1 += ks1;
#define TF_R(r) { x0 += x1; x1 = tf_rotl32(x1, r); x1 ^= x0; }
  TF_R(13) TF_R(15) TF_R(26) TF_R(6)
  x0 += ks1; x1 += ks2 + 1u;
  TF_R(17) TF_R(29) TF_R(16) TF_R(24)
  x0 += ks2; x1 += ks0 + 2u;
  TF_R(13) TF_R(15) TF_R(26) TF_R(6)
  x0 += ks0; x1 += ks1 + 3u;
  TF_R(17) TF_R(29) TF_R(16) TF_R(24)
  x0 += ks1; x1 += ks2 + 4u;
  TF_R(13) TF_R(15) TF_R(26) TF_R(6)
  x0 += ks2; x1 += ks0 + 5u;
#undef TF_R
  *o0 = x0; *o1 = x1;
}

// ---------------------------------------------------------------------------
// Problem dims
// ---------------------------------------------------------------------------
#define BSZ   8192
#define KIN   784
#define HID   800
#define NOUT  10
#define NSTEP 25

// R8: golden = Eigen gebp (AVX no-FMA jaxlib): k-panels [0,264) [264,528)
// [528,784), per k-step acc = rn(acc + rn(a*b)); C = 0.5*rn(rn(P0+P1)+P2).
// R9: a in {0,1,2} makes every product exact, so fmaf == mul+add bit-exactly.
// R13/R15/R16 empirical law: wall tracks WAVE COUNT, not inner instr count
//   (6400 waves -> 169-175us at 40 or 24 cyc/kk; 3200 waves -> 198-249us).
//   Gemm is latency/parallelism-bound at 1600 blocks (~38% occ).
// R17 (this round): K-split by Eigen panel — panels are INDEPENDENT chains,
//   combined only at the end. Grid x3 (blockIdx.z = panel), BK=8 (33/33/32
//   full tiles/panel), each block writes a raw partial gp[panel]; update
//   kernel does the exact combine 0.5*rn(rn(P0+P1)+P2). Inner loop loses the
//   PANEL compares and tot registers. 4800 blocks = 19200 waves (2.3x
//   oversubscription). Cost: +~100MB/step HBM (partials). Predict gemm
//   169 -> 90-120us; if >=150, parallelism isn't the limiter (pivot).
// ---------------------------------------------------------------------------

// ---------------------------------------------------------------------------
// Kernel 1: Poisson encoding (JAX-faithful: truncated 2^-23 grid).
// enc = temp + 1 in {0,1,2}; sp = 0.5*enc (exact power-of-2 relation).
// ---------------------------------------------------------------------------
__global__ __launch_bounds__(256) void enc_kernel(const float* __restrict__ inp,
                                                  uint8_t* __restrict__ enc,
                                                  uint32_t k0, uint32_t k1) {
  int j = blockIdx.x * blockDim.x + threadIdx.x;
  if (j >= BSZ * KIN) return;
  uint32_t o0, o1;
  threefry2x32(k0, k1, 0u, (uint32_t)j, &o0, &o1);
  uint32_t bits = o0 ^ o1;
  float r = __uint_as_float((bits >> 9) | 0x3f800000u) - 1.0f;
  float x = inp[j];
  bool cond = (2.0f * r <= fabsf(x));
  int s = (x > 0.0f) ? 1 : ((x < 0.0f) ? -1 : 0);
  enc[j] = (uint8_t)(1 + (cond ? s : 0));
}

// ---------------------------------------------------------------------------
// Kernel 2: panel partial Pz[b,j] for panel z = blockIdx.z.
// BM=128, BN=32, BK=8. 256 threads (4 waves), 4x4 acc per thread.
// As: packed u8 [2][BK][BM/4 words]; Bs: f32 [2][BK][BN]. Double-buffered;
// wave0 stages A, wave2 stages B; one barrier per tile.
// Per kk: ds_read_b32 (A bcast) + ds_read_b128 (B bcast) + 4 cvt + 8 pk_fma.
// ---------------------------------------------------------------------------
#define BM 128
#define BN 32
#define BK 8

typedef float f32x2 __attribute__((ext_vector_type(2)));

__device__ __forceinline__ float cvt_ub(uint32_t x, int i) {
  return (float)((x >> (8 * i)) & 0xffu);   // folds to v_cvt_f32_ubyte_i
}

// acc.lo = fma(a.lo, b.lo, acc.lo); acc.hi = fma(a.lo, b.hi, acc.hi)
// Per-half rounding == v_fma_f32 (bit-exact); src0 half broadcast via op_sel.
__device__ __forceinline__ void pk_fma_lo(f32x2& acc, f32x2 a, f32x2 b) {
  asm("v_pk_fma_f32 %0, %1, %2, %0 op_sel:[0,0,0] op_sel_hi:[0,1,1]"
      : "+v"(acc)
      : "v"(a), "v"(b));
}
// same but broadcasting src0.hi
__device__ __forceinline__ void pk_fma_hi(f32x2& acc, f32x2 a, f32x2 b) {
  asm("v_pk_fma_f32 %0, %1, %2, %0 op_sel:[1,0,0] op_sel_hi:[1,1,1]"
      : "+v"(acc)
      : "v"(a), "v"(b));
}

__global__ __launch_bounds__(256) void gemm_kernel(const uint8_t* __restrict__ enc,
                                                   const float* __restrict__ w1,
                                                   float* __restrict__ gp) {
  __shared__ uint32_t As[2][BK][BM / 4];  // 2 x 1 KB
  __shared__ float    Bs[2][BK][BN];      // 2 x 1 KB
  const int panel  = blockIdx.z;
  const int kstart = (panel == 0) ? 0 : ((panel == 1) ? 264 : 528);
  const int ntile  = (panel == 2) ? 32 : 33;
  const int m0 = blockIdx.x * BM;
  const int n0 = blockIdx.y * BN;
  const int t  = threadIdx.x;

  // compute mapping: 32 row-groups x 8 col-groups, 4x4 per thread
  const int tm = t / 8;        // 0..31 -> rows tm*4 .. +3
  const int tn = t % 8;        // 0..7  -> cols tn*4 .. +3

  // staging roles: wave0 (t<64) stages A: 4 rows x 4 k bytes each;
  //                wave2 (128<=t<192) stages B: 1 row x 4 k f32 each.
  const bool stA = (t < 64);
  const bool stB = (t >= 128 && t < 192);
  const int ar0 = (t & 31) * 4;          // A: row base 0..124
  const int ak0 = ((t >> 5) & 1) * 4;    // A: k base 0,4
  const int ub   = (t - 128) & 63;
  const int brow = ub & 31;              // B: row 0..31
  const int bk0  = (ub >> 5) * 4;        // B: k base 0,4

  const uint8_t* aptr = enc + (size_t)(m0 + ar0) * KIN + kstart + ak0;
  const float*   bptr = w1 + (size_t)(n0 + brow) * KIN + kstart + bk0;

  uint32_t rA0, rA1, rA2, rA3;
  float4 rB;

  f32x2 acc[4][2];   // single panel chain: [mi][nj] covers cols 2nj,2nj+1
#pragma unroll
  for (int mi = 0; mi < 4; mi++)
#pragma unroll
    for (int nj = 0; nj < 2; nj++) acc[mi][nj] = (f32x2)(0.0f);

#define LOAD_TILE(KOFF)                                              \
  {                                                                  \
    if (stA) {                                                       \
      const uint8_t* ap = aptr + (KOFF);                             \
      rA0 = *(const uint32_t*)(ap + (size_t)0 * KIN);                \
      rA1 = *(const uint32_t*)(ap + (size_t)1 * KIN);                \
      rA2 = *(const uint32_t*)(ap + (size_t)2 * KIN);                \
      rA3 = *(const uint32_t*)(ap + (size_t)3 * KIN);                \
    }                                                                \
    if (stB) rB = *(const float4*)(bptr + (KOFF));                   \
  }

#define STORE_TILE(P)                                                \
  {                                                                  \
    if (stA) {                                                       \
      uint32_t a01  = __builtin_amdgcn_perm(rA1, rA0, 0x05010400u);  \
      uint32_t a01h = __builtin_amdgcn_perm(rA1, rA0, 0x07030602u);  \
      uint32_t a23  = __builtin_amdgcn_perm(rA3, rA2, 0x05010400u);  \
      uint32_t a23h = __builtin_amdgcn_perm(rA3, rA2, 0x07030602u);  \
      As[P][ak0 + 0][ar0 >> 2] = __builtin_amdgcn_perm(a23,  a01,  0x05040100u); \
      As[P][ak0 + 1][ar0 >> 2] = __builtin_amdgcn_perm(a23,  a01,  0x07060302u); \
      As[P][ak0 + 2][ar0 >> 2] = __builtin_amdgcn_perm(a23h, a01h, 0x05040100u); \
      As[P][ak0 + 3][ar0 >> 2] = __builtin_amdgcn_perm(a23h, a01h, 0x07060302u); \
    }                                                                \
    if (stB) {                                                       \
      Bs[P][bk0 + 0][brow] = rB.x;                                   \
      Bs[P][bk0 + 1][brow] = rB.y;                                   \
      Bs[P][bk0 + 2][brow] = rB.z;                                   \
      Bs[P][bk0 + 3][brow] = rB.w;                                   \
    }                                                                \
  }

  // ---- prologue: stage tile 0 into buffer 0 ----
  LOAD_TILE(0)
  STORE_TILE(0)
  __syncthreads();

  int p = 0;
  for (int tile = 0; tile < ntile; tile++) {
    const bool more = (tile + 1 < ntile);
    // issue next tile's global loads; latency hides under compute
    if (more) { LOAD_TILE((size_t)(tile + 1) * BK) }
    // compute current tile from LDS buffer p (ascending k chain)
    {
      const uint32_t* arow = &As[p][0][tm];
      const float*    brw  = &Bs[p][0][tn * 4];
#pragma unroll
      for (int kk = 0; kk < BK; kk++) {
        uint32_t aw = arow[(size_t)kk * (BM / 4)];
        float4 bv = *(const float4*)(brw + (size_t)kk * BN);
        f32x2 am[2];
        am[0].x = cvt_ub(aw, 0); am[0].y = cvt_ub(aw, 1);
        am[1].x = cvt_ub(aw, 2); am[1].y = cvt_ub(aw, 3);
        f32x2 b2[2];
        b2[0].x = bv.x; b2[0].y = bv.y;
        b2[1].x = bv.z; b2[1].y = bv.w;
        // rows: mi = 2*mp + h (h = broadcast half of am[mp])
#pragma unroll
        for (int mp = 0; mp < 2; mp++) {
          pk_fma_lo(acc[2 * mp + 0][0], am[mp], b2[0]);
          pk_fma_lo(acc[2 * mp + 0][1], am[mp], b2[1]);
          pk_fma_hi(acc[2 * mp + 1][0], am[mp], b2[0]);
          pk_fma_hi(acc[2 * mp + 1][1], am[mp], b2[1]);
        }
      }
    }
    // stage next tile into the other buffer (no reader until after sync)
    if (more) { STORE_TILE(p ^ 1) }
    __syncthreads();
    p ^= 1;
  }
#undef LOAD_TILE
#undef STORE_TILE

  // epilogue: write RAW panel partial (combine happens in update_kernel)
  float* base = gp + (size_t)panel * BSZ * HID;
#pragma unroll
  for (int mi = 0; mi < 4; mi++) {
    float* dst = base + (size_t)(m0 + tm * 4 + mi) * HID + n0 + tn * 4;
    float4 o;
    o.x = acc[mi][0].x;
    o.y = acc[mi][0].y;
    o.z = acc[mi][1].x;
    o.w = acc[mi][1].y;
    *(float4*)dst = o;
  }
}

// ---------------------------------------------------------------------------
// Kernel 3: combine panels (exact Eigen order) + membrane update + spike +
// mem2 accumulation.
// g = 0.5 * rn(rn(P0+P1) + P2)   (0.5 exact)
// m = rn(rn(0.95f*mem) + rn(0.05f*g)) — mul/mul/add; products NOT exact here,
// so FMA contraction would change bits — keep split __fmul_rn/__fadd_rn.
// ---------------------------------------------------------------------------
__global__ __launch_bounds__(256) void update_kernel(const float* __restrict__ gp,
                                                     float* __restrict__ mem1,
                                                     const float* __restrict__ w2,
                                                     float* __restrict__ mem2) {
  __shared__ float w2s[NOUT * HID];   // 32 KB
  for (int i = threadIdx.x; i < NOUT * HID; i += 256) w2s[i] = w2[i];
  __syncthreads();

  const int wave = threadIdx.x / 64;
  const int lane = threadIdx.x % 64;
  const int b = blockIdx.x * 4 + wave;

  const size_t GS = (size_t)BSZ * HID;
  const float* g0 = gp + (size_t)b * HID;
  const float* g1 = g0 + GS;
  const float* g2 = g1 + GS;
  float* mrow = mem1 + (size_t)b * HID;

  float acc[NOUT];
#pragma unroll
  for (int i = 0; i < NOUT; i++) acc[i] = 0.0f;

  for (int j = lane; j < HID; j += 64) {
    float gs = __fmul_rn(0.5f, __fadd_rn(__fadd_rn(g0[j], g1[j]), g2[j]));
    float m = __fadd_rn(__fmul_rn(0.95f, mrow[j]), __fmul_rn(0.05f, gs));
    bool spike = __fadd_rn(m, -1.0f) > 0.0f;
    mrow[j] = spike ? __fadd_rn(m, -1.0f) : m;
    if (spike) {
#pragma unroll
      for (int i = 0; i < NOUT; i++) acc[i] += w2s[i * HID + j];
    }
  }
  // mem2 never feeds back into spike decisions: reduction-order noise ~1e-7
  // << 3.6e-3 threshold, no need to replicate ref's order here.
#pragma unroll
  for (int i = 0; i < NOUT; i++) {
    float v = acc[i];
    for (int off = 32; off > 0; off >>= 1) v += __shfl_down(v, off);
    if (lane == 0) mem2[(size_t)b * NOUT + i] += v;
  }
}

// ---------------------------------------------------------------------------
// Kernel 4: out = mem2 / num_steps
// ---------------------------------------------------------------------------
__global__ __launch_bounds__(256) void finalize_kernel(const float* __restrict__ mem2,
                                                       const int* __restrict__ ns,
                                                       float* __restrict__ out) {
  int i = blockIdx.x * blockDim.x + threadIdx.x;
  if (i < BSZ * NOUT) out[i] = mem2[i] / (float)(*ns);
}

// ---------------------------------------------------------------------------
extern "C" void kernel_launch(void* const* d_in, const int* in_sizes, int n_in,
                              void* d_out, int out_size, void* d_ws, size_t ws_size,
                              hipStream_t stream) {
  const float* inp = (const float*)d_in[0];
  const float* w1  = (const float*)d_in[1];
  const float* w2  = (const float*)d_in[2];
  const int*   dns = (const int*)d_in[3];
  float* out = (float*)d_out;

  char* ws = (char*)d_ws;
  size_t off = 0;
  uint8_t* enc = (uint8_t*)(ws + off);  off += (size_t)BSZ * KIN;          // 6.4 MB
  off = (off + 255) & ~(size_t)255;
  float* gp   = (float*)(ws + off);     off += (size_t)3 * BSZ * HID * 4;  // 78.6 MB
  float* mem1 = (float*)(ws + off);     off += (size_t)BSZ * HID * 4;      // 26.2 MB
  float* mem2 = (float*)(ws + off);     off += (size_t)BSZ * NOUT * 4;     // 0.33 MB

  (void)hipMemsetAsync(mem1, 0, (size_t)BSZ * HID * 4, stream);
  (void)hipMemsetAsync(mem2, 0, (size_t)BSZ * NOUT * 4, stream);

  // Step keys: partitionable split — key_t = threefry((0,42), (0,t)).
  uint32_t keys[NSTEP][2];
  for (int t = 0; t < NSTEP; t++)
    threefry2x32(0u, 42u, 0u, (uint32_t)t, &keys[t][0], &keys[t][1]);

  const int n_elem = BSZ * KIN;
  for (int t = 0; t < NSTEP; t++) {
    enc_kernel<<<(n_elem + 255) / 256, 256, 0, stream>>>(inp, enc, keys[t][0], keys[t][1]);
    gemm_kernel<<<dim3(BSZ / BM, HID / BN, 3), 256, 0, stream>>>(enc, w1, gp);
    update_kernel<<<BSZ / 4, 256, 0, stream>>>(gp, mem1, w2, mem2);
  }
  finalize_kernel<<<(BSZ * NOUT + 255) / 256, 256, 0, stream>>>(mem2, dns, out);
}